// Round 12
// baseline (119.458 us; speedup 1.0000x reference)
//
#include <hip/hip_runtime.h>
#include <math.h>

#define NEG_SLOPE 0.01f

// ---------------------------------------------------------------------------
// Kernel 1 (fused independent prep)  [R9/R10/R11-verified, unchanged]:
//   blocks [0,256):    1x1 conv 16<-384 + bias + leaky  -> x16 (4,16,32,32)
//   blocks [256,4288): guide pyramids g256/g128/g64 as exact 2x2 box filters.
// Resize identity: for R in {64,128,256}, (o+0.5)*(512/R)-0.5 has frac exactly
// 0.5 and interior indices -> each output is a 2x2 box filter.
// ---------------------------------------------------------------------------
__global__ void __launch_bounds__(256)
prep_kernel(const float* __restrict__ x, const float* __restrict__ lw,
            const float* __restrict__ lb, float* __restrict__ x16,
            const float* __restrict__ g, float* __restrict__ g64p,
            float* __restrict__ g128p, float* __restrict__ g256p) {
    int bid = blockIdx.x;
    if (bid < 256) {
        int idx = bid * 256 + threadIdx.x;
        int hw = idx & 1023, co = (idx >> 10) & 15, bb = idx >> 14;
        const float* xp = x + bb * 384 * 1024 + hw;
        const float* wp = lw + co * 384;
        float a0 = 0.f, a1 = 0.f, a2 = 0.f, a3 = 0.f;
        for (int ci = 0; ci < 384; ci += 4) {
            a0 = fmaf(wp[ci],     xp[(ci)     * 1024], a0);
            a1 = fmaf(wp[ci + 1], xp[(ci + 1) * 1024], a1);
            a2 = fmaf(wp[ci + 2], xp[(ci + 2) * 1024], a2);
            a3 = fmaf(wp[ci + 3], xp[(ci + 3) * 1024], a3);
        }
        float acc = lb[co] + ((a0 + a1) + (a2 + a3));
        x16[idx] = acc >= 0.f ? acc : NEG_SLOPE * acc;
    } else {
        int idx = (bid - 256) * 256 + threadIdx.x;   // 1032192 px total
        if (idx < 786432) {                          // g256: 2x2 box at (2r,2c)
            int o = idx;
            int c = o & 255, r = (o >> 8) & 255, bc = o >> 16;
            const float2* gp2 = (const float2*)(g + (size_t)bc * 262144);
            float2 a = gp2[(2 * r) * 256 + c];
            float2 b = gp2[(2 * r + 1) * 256 + c];
            g256p[o] = 0.25f * ((a.x + a.y) + (b.x + b.y));
        } else if (idx < 983040) {                   // g128: box at (4r+1,4c+1)
            int o = idx - 786432;
            int c = o & 127, r = (o >> 7) & 127, bc = o >> 14;
            const float* gp = g + (size_t)bc * 262144;
            int a0 = (4 * r + 1) * 512 + 4 * c + 1;
            int a1 = a0 + 512;
            g128p[o] = 0.25f * ((gp[a0] + gp[a0 + 1]) + (gp[a1] + gp[a1 + 1]));
        } else {                                     // g64: box at (8r+3,8c+3)
            int o = idx - 983040;
            int c = o & 63, r = (o >> 6) & 63, bc = o >> 12;
            const float* gp = g + (size_t)bc * 262144;
            int a0 = (8 * r + 3) * 512 + 8 * c + 3;
            int a1 = a0 + 512;
            g64p[o] = 0.25f * ((gp[a0] + gp[a0 + 1]) + (gp[a1] + gp[a1 + 1]));
        }
    }
}

// ---------------------------------------------------------------------------
// In-LDS PAC stage — verified math, all dims compile-time (no int div).
// ---------------------------------------------------------------------------
template <int Ci, int Co, int NX, int NG, int NO, int RES>
__device__ inline void pac_lds(const float* __restrict__ sx, int BXr, int BXc,
                               const float* __restrict__ sg, int BGr, int BGc,
                               const float* __restrict__ sw, float* __restrict__ so,
                               int BOr, int BOc) {
    constexpr int NG2 = NG * NG, NX2 = NX * NX, NO2 = NO * NO;
    for (int i = threadIdx.x; i < NO2; i += 256) {
        int r = i / NO, c = i % NO;
        int gh = BOr + r, gw = BOc + c;
        float acc[Co];
#pragma unroll
        for (int co = 0; co < Co; ++co) acc[co] = 0.f;
        if (gh >= 0 && gh < RES && gw >= 0 && gw < RES) {
            int lc0 = (gh - BGr) * NG + (gw - BGc);
            float gc0 = sg[lc0], gc1 = sg[NG2 + lc0], gc2 = sg[2 * NG2 + lc0];
#pragma unroll
            for (int tt = 0; tt < 9; ++tt) {
                int hh = gh + tt / 3 - 1, ww = gw + tt % 3 - 1;
                if (hh < 0 || hh >= RES || ww < 0 || ww >= RES) continue;
                int lt = (hh - BGr) * NG + (ww - BGc);
                float d0 = sg[lt] - gc0;
                float d1 = sg[NG2 + lt] - gc1;
                float d2 = sg[2 * NG2 + lt] - gc2;
                float k = __expf(-0.5f * (d0 * d0 + d1 * d1 + d2 * d2));
                int lx = ((hh >> 1) - BXr) * NX + ((ww >> 1) - BXc);
#pragma unroll
                for (int ci = 0; ci < Ci; ++ci) {
                    float xv = sx[ci * NX2 + lx] * k;
#pragma unroll
                    for (int co = 0; co < Co; ++co)
                        acc[co] = fmaf(sw[(co * Ci + ci) * 9 + tt], xv, acc[co]);
                }
            }
        }
#pragma unroll
        for (int co = 0; co < Co; ++co) {
            float v = acc[co];
            so[co * NO2 + i] = v >= 0.f ? v : NEG_SLOPE * v;
        }
    }
}

// ---------------------------------------------------------------------------
// Kernel 2: fused pac@64 + pac@128 per 16x16 x1-tile [R11-verified, unchanged].
// x1 output channel-interleaved [4][128][128][4], single float4 store/px.
// ---------------------------------------------------------------------------
__global__ void __launch_bounds__(256)
pac_mid_kernel(const float* __restrict__ x16g, const float* __restrict__ g64p,
               const float* __restrict__ g128p,
               const float* __restrict__ w0, const float* __restrict__ w1,
               float* __restrict__ x1p) {
    __shared__ float smem[3100];
    float* sw0   = smem;            // 576
    float* sw1   = smem + 576;      // 144
    float* sx16  = smem + 720;      // 576  [16][6][6]
    float* sg64  = smem + 1296;     // 432  [3][12][12]
    float* sg128 = smem + 1728;     // 972  [3][18][18]
    float* sx0   = smem + 2700;     // 400  [4][10][10]

    int bid = blockIdx.x;           // 256
    int b = bid >> 6;
    int t = (bid >> 3) & 7;         // tileY
    int u = bid & 7;                // tileX

    const int BXr = 4 * t - 1,  BXc = 4 * u - 1;    // x16 (32-res), 6
    const int BG0r = 8 * t - 2, BG0c = 8 * u - 2;   // g64, 12
    const int B0r = 8 * t - 1,  B0c = 8 * u - 1;    // x0 (64-res), 10
    const int BG1r = 16 * t - 1, BG1c = 16 * u - 1; // g128, 18

    for (int i = threadIdx.x; i < 576; i += 256) sw0[i] = w0[i];
    for (int i = threadIdx.x; i < 144; i += 256) sw1[i] = w1[i];
    for (int i = threadIdx.x; i < 576; i += 256) {           // x16 [16][6][6]
        int ci = i / 36, rem = i % 36, r = rem / 6, c = rem % 6;
        int gr = BXr + r, gc = BXc + c;
        float v = 0.f;
        if (gr >= 0 && gr < 32 && gc >= 0 && gc < 32)
            v = x16g[((b * 16 + ci) << 10) + (gr << 5) + gc];
        sx16[i] = v;
    }
    for (int i = threadIdx.x; i < 432; i += 256) {           // g64 [3][12][12]
        int ch = i / 144, rem = i % 144, r = rem / 12, c = rem % 12;
        int gr = BG0r + r, gc = BG0c + c;
        float v = 0.f;
        if (gr >= 0 && gr < 64 && gc >= 0 && gc < 64)
            v = g64p[(b * 3 + ch) * 4096 + (gr << 6) + gc];
        sg64[i] = v;
    }
    for (int i = threadIdx.x; i < 972; i += 256) {           // g128 [3][18][18]
        int ch = i / 324, rem = i % 324, r = rem / 18, c = rem % 18;
        int gr = BG1r + r, gc = BG1c + c;
        float v = 0.f;
        if (gr >= 0 && gr < 128 && gc >= 0 && gc < 128)
            v = g128p[(b * 3 + ch) * 16384 + (gr << 7) + gc];
        sg128[i] = v;
    }
    __syncthreads();

    // Phase 1: x0 halo tile @64
    pac_lds<16, 4, 6, 12, 10, 64>(sx16, BXr, BXc, sg64, BG0r, BG0c, sw0, sx0, B0r, B0c);
    __syncthreads();

    // Phase 2: x1 16x16 @128 -> global packed float4 (leaky). 1 px/thread.
    {
        int i = threadIdx.x;
        int r = i >> 4, c = i & 15;
        int gh = 16 * t + r, gw = 16 * u + c;
        int lc0 = (gh - BG1r) * 18 + (gw - BG1c);
        float gc0 = sg128[lc0], gc1 = sg128[324 + lc0], gc2 = sg128[648 + lc0];
        float acc[4] = {0.f, 0.f, 0.f, 0.f};
#pragma unroll
        for (int tt = 0; tt < 9; ++tt) {
            int hh = gh + tt / 3 - 1, ww = gw + tt % 3 - 1;
            if (hh < 0 || hh >= 128 || ww < 0 || ww >= 128) continue;
            int lt = (hh - BG1r) * 18 + (ww - BG1c);
            float d0 = sg128[lt] - gc0;
            float d1 = sg128[324 + lt] - gc1;
            float d2 = sg128[648 + lt] - gc2;
            float k = __expf(-0.5f * (d0 * d0 + d1 * d1 + d2 * d2));
            int lx = ((hh >> 1) - B0r) * 10 + ((ww >> 1) - B0c);
#pragma unroll
            for (int ci = 0; ci < 4; ++ci) {
                float xv = sx0[ci * 100 + lx] * k;
#pragma unroll
                for (int co = 0; co < 4; ++co)
                    acc[co] = fmaf(sw1[(co * 4 + ci) * 9 + tt], xv, acc[co]);
            }
        }
        float4 o4;
        o4.x = acc[0] >= 0.f ? acc[0] : NEG_SLOPE * acc[0];
        o4.y = acc[1] >= 0.f ? acc[1] : NEG_SLOPE * acc[1];
        o4.z = acc[2] >= 0.f ? acc[2] : NEG_SLOPE * acc[2];
        o4.w = acc[3] >= 0.f ? acc[3] : NEG_SLOPE * acc[3];
        ((float4*)x1p)[(b << 14) + (gh << 7) + gw] = o4;
    }
}

// ---------------------------------------------------------------------------
// Kernel 3: pac 4->4 @256 + leaky, one thread per 2x2 output quad.
// NEW: R8-verified quad pattern applied at the 256 level. Quad shares a
// 4x4x3 g256 window (48 loads) and a 3x3 packed-float4 x1 window (9 loads);
// 4 packed float4 stores. Index algebra identical to pac512_quad.
// 65536 quads -> 256 blocks x 256 threads.
// ---------------------------------------------------------------------------
__global__ void __launch_bounds__(256)
pac256_quad_kernel(const float* __restrict__ x1p, const float* __restrict__ g256p,
                   const float* __restrict__ w2, float* __restrict__ x2p) {
    __shared__ float sw[144];
    if (threadIdx.x < 144) sw[threadIdx.x] = w2[threadIdx.x];
    __syncthreads();

    int idx = blockIdx.x * 256 + threadIdx.x;   // 65536 quads
    int qw = idx & 127;
    int qh = (idx >> 7) & 127;
    int b = idx >> 14;
    int h0 = qh << 1, w0 = qw << 1;             // 256-res coords

    const float* gb = g256p + (size_t)b * 3 * 65536;
    const float4* xb4 = (const float4*)x1p + (size_t)b * 16384;

    // g256 window [3][4][4]: rows h0-1..h0+2, cols w0-1..w0+2 (0 for OOB slots)
    float gw[3][4][4];
#pragma unroll
    for (int rr = 0; rr < 4; ++rr) {
        int gr = h0 - 1 + rr;
        bool rok = (gr >= 0 && gr < 256);
#pragma unroll
        for (int cc = 0; cc < 4; ++cc) {
            int gc = w0 - 1 + cc;
            bool ok = rok && (gc >= 0 && gc < 256);
            int a = (gr << 8) + gc;
#pragma unroll
            for (int ch = 0; ch < 3; ++ch)
                gw[ch][rr][cc] = ok ? gb[ch * 65536 + a] : 0.f;
        }
    }
    // x1 window [3][3] float4: rows qh-1..qh+1, cols qw-1..qw+1 at 128-res
    float xw[4][3][3];
#pragma unroll
    for (int rr = 0; rr < 3; ++rr) {
        int xr = qh - 1 + rr;
        bool rok = (xr >= 0 && xr < 128);
#pragma unroll
        for (int cc = 0; cc < 3; ++cc) {
            int xc = qw - 1 + cc;
            bool ok = rok && (xc >= 0 && xc < 128);
            float4 v = ok ? xb4[(xr << 7) + xc] : make_float4(0.f, 0.f, 0.f, 0.f);
            xw[0][rr][cc] = v.x;
            xw[1][rr][cc] = v.y;
            xw[2][rr][cc] = v.z;
            xw[3][rr][cc] = v.w;
        }
    }

    float4* ob4 = (float4*)x2p + (size_t)b * 65536;
#pragma unroll
    for (int dr = 0; dr < 2; ++dr) {
#pragma unroll
        for (int dc = 0; dc < 2; ++dc) {
            float gc0 = gw[0][dr + 1][dc + 1];
            float gc1 = gw[1][dr + 1][dc + 1];
            float gc2 = gw[2][dr + 1][dc + 1];
            float acc[4] = {0.f, 0.f, 0.f, 0.f};
#pragma unroll
            for (int tt = 0; tt < 9; ++tt) {
                const int th = tt / 3, tc = tt % 3;
                int hh = h0 + dr + th - 1, ww = w0 + dc + tc - 1;
                if (hh < 0 || hh >= 256 || ww < 0 || ww >= 256) continue;
                float d0 = gw[0][dr + th][dc + tc] - gc0;
                float d1 = gw[1][dr + th][dc + tc] - gc1;
                float d2 = gw[2][dr + th][dc + tc] - gc2;
                float k = __expf(-0.5f * (d0 * d0 + d1 * d1 + d2 * d2));
                const int xr = ((dr + th - 1) >> 1) + 1;
                const int xc = ((dc + tc - 1) >> 1) + 1;
#pragma unroll
                for (int ci = 0; ci < 4; ++ci) {
                    float xv = xw[ci][xr][xc] * k;
#pragma unroll
                    for (int co = 0; co < 4; ++co)
                        acc[co] = fmaf(sw[(co * 4 + ci) * 9 + tt], xv, acc[co]);
                }
            }
            float4 o4;
            o4.x = acc[0] >= 0.f ? acc[0] : NEG_SLOPE * acc[0];
            o4.y = acc[1] >= 0.f ? acc[1] : NEG_SLOPE * acc[1];
            o4.z = acc[2] >= 0.f ? acc[2] : NEG_SLOPE * acc[2];
            o4.w = acc[3] >= 0.f ? acc[3] : NEG_SLOPE * acc[3];
            ob4[((h0 + dr) << 8) + (w0 + dc)] = o4;
        }
    }
}

// ---------------------------------------------------------------------------
// Kernel 4: pac 4->1 @512 + sigmoid, one thread per 2x2 output quad
// [R11-verified, unchanged]. x2 input packed float4.
// ---------------------------------------------------------------------------
__global__ void __launch_bounds__(256)
pac512_quad_kernel(const float* __restrict__ x2p, const float* __restrict__ guide,
                   const float* __restrict__ w3, float* __restrict__ out) {
    __shared__ float sw[36];
    if (threadIdx.x < 36) sw[threadIdx.x] = w3[threadIdx.x];
    __syncthreads();

    int idx = blockIdx.x * 256 + threadIdx.x;   // 262144 quads
    int qw = idx & 255;
    int qh = (idx >> 8) & 255;
    int b = idx >> 16;
    int h0 = qh << 1, w0 = qw << 1;

    const float* gb = guide + (size_t)b * 3 * 262144;
    const float4* xb4 = (const float4*)x2p + (size_t)b * 65536;

    float gw[3][4][4];
#pragma unroll
    for (int rr = 0; rr < 4; ++rr) {
        int gr = h0 - 1 + rr;
        bool rok = (gr >= 0 && gr < 512);
#pragma unroll
        for (int cc = 0; cc < 4; ++cc) {
            int gc = w0 - 1 + cc;
            bool ok = rok && (gc >= 0 && gc < 512);
            int a = (gr << 9) + gc;
#pragma unroll
            for (int ch = 0; ch < 3; ++ch)
                gw[ch][rr][cc] = ok ? gb[ch * 262144 + a] : 0.f;
        }
    }
    float xw[4][3][3];
#pragma unroll
    for (int rr = 0; rr < 3; ++rr) {
        int xr = qh - 1 + rr;
        bool rok = (xr >= 0 && xr < 256);
#pragma unroll
        for (int cc = 0; cc < 3; ++cc) {
            int xc = qw - 1 + cc;
            bool ok = rok && (xc >= 0 && xc < 256);
            float4 v = ok ? xb4[(xr << 8) + xc] : make_float4(0.f, 0.f, 0.f, 0.f);
            xw[0][rr][cc] = v.x;
            xw[1][rr][cc] = v.y;
            xw[2][rr][cc] = v.z;
            xw[3][rr][cc] = v.w;
        }
    }

    float* ob = out + (size_t)b * 262144;
#pragma unroll
    for (int dr = 0; dr < 2; ++dr) {
#pragma unroll
        for (int dc = 0; dc < 2; ++dc) {
            float gc0 = gw[0][dr + 1][dc + 1];
            float gc1 = gw[1][dr + 1][dc + 1];
            float gc2 = gw[2][dr + 1][dc + 1];
            float acc = 0.f;
#pragma unroll
            for (int tt = 0; tt < 9; ++tt) {
                const int th = tt / 3, tc = tt % 3;
                int hh = h0 + dr + th - 1, ww = w0 + dc + tc - 1;
                if (hh < 0 || hh >= 512 || ww < 0 || ww >= 512) continue;
                float d0 = gw[0][dr + th][dc + tc] - gc0;
                float d1 = gw[1][dr + th][dc + tc] - gc1;
                float d2 = gw[2][dr + th][dc + tc] - gc2;
                float k = __expf(-0.5f * (d0 * d0 + d1 * d1 + d2 * d2));
                const int xr = ((dr + th - 1) >> 1) + 1;
                const int xc = ((dc + tc - 1) >> 1) + 1;
#pragma unroll
                for (int ci = 0; ci < 4; ++ci)
                    acc = fmaf(sw[ci * 9 + tt], xw[ci][xr][xc] * k, acc);
            }
            ob[((h0 + dr) << 9) + (w0 + dc)] = 1.0f / (1.0f + __expf(-acc));
        }
    }
}

extern "C" void kernel_launch(void* const* d_in, const int* in_sizes, int n_in,
                              void* d_out, int out_size, void* d_ws, size_t ws_size,
                              hipStream_t stream) {
    const float* x     = (const float*)d_in[0];   // (4,384,32,32)
    const float* guide = (const float*)d_in[1];   // (4,3,512,512)
    const float* lin_w = (const float*)d_in[2];   // (16,384,1,1)
    const float* lin_b = (const float*)d_in[3];   // (16,)
    const float* w0    = (const float*)d_in[4];   // (4,16,3,3)
    const float* w1    = (const float*)d_in[5];   // (4,4,3,3)
    const float* w2    = (const float*)d_in[6];   // (4,4,3,3)
    const float* w3    = (const float*)d_in[7];   // (1,4,3,3)
    float* out = (float*)d_out;                   // (4,1,512,512)

    float* ws    = (float*)d_ws;
    float* x16   = ws;                 // 65536
    float* g64p  = x16 + 65536;        // 49152    (4,3,64,64)
    float* g128p = g64p + 49152;       // 196608   (4,3,128,128)
    float* g256p = g128p + 196608;     // 786432   (4,3,256,256)
    float* x1p   = g256p + 786432;     // 262144   (4,128,128,4) packed, 16B-aligned
    float* x2p   = x1p + 262144;       // 1048576  (4,256,256,4) packed, 16B-aligned

    prep_kernel<<<4288, 256, 0, stream>>>(x, lin_w, lin_b, x16, guide, g64p, g128p, g256p);
    pac_mid_kernel<<<256, 256, 0, stream>>>(x16, g64p, g128p, w0, w1, x1p);
    pac256_quad_kernel<<<256, 256, 0, stream>>>(x1p, g256p, w2, x2p);
    pac512_quad_kernel<<<1024, 256, 0, stream>>>(x2p, guide, w3, out);
}

// Round 13
// 117.036 us; speedup vs baseline: 1.0207x; 1.0207x over previous
//
#include <hip/hip_runtime.h>
#include <math.h>

#define NEG_SLOPE 0.01f

// ---------------------------------------------------------------------------
// Kernel 1 (fused independent prep)  [R9/R10/R11-verified]:
//   blocks [0,256):    1x1 conv 16<-384 + bias + leaky  -> x16 (4,16,32,32)
//   blocks [256,4288): guide pyramids g256/g128/g64 as exact 2x2 box filters.
// Resize identity: for R in {64,128,256}, (o+0.5)*(512/R)-0.5 has frac exactly
// 0.5 and interior indices -> each output is a 2x2 box filter.
// ---------------------------------------------------------------------------
__global__ void __launch_bounds__(256)
prep_kernel(const float* __restrict__ x, const float* __restrict__ lw,
            const float* __restrict__ lb, float* __restrict__ x16,
            const float* __restrict__ g, float* __restrict__ g64p,
            float* __restrict__ g128p, float* __restrict__ g256p) {
    int bid = blockIdx.x;
    if (bid < 256) {
        int idx = bid * 256 + threadIdx.x;
        int hw = idx & 1023, co = (idx >> 10) & 15, bb = idx >> 14;
        const float* xp = x + bb * 384 * 1024 + hw;
        const float* wp = lw + co * 384;
        float a0 = 0.f, a1 = 0.f, a2 = 0.f, a3 = 0.f;
        for (int ci = 0; ci < 384; ci += 4) {
            a0 = fmaf(wp[ci],     xp[(ci)     * 1024], a0);
            a1 = fmaf(wp[ci + 1], xp[(ci + 1) * 1024], a1);
            a2 = fmaf(wp[ci + 2], xp[(ci + 2) * 1024], a2);
            a3 = fmaf(wp[ci + 3], xp[(ci + 3) * 1024], a3);
        }
        float acc = lb[co] + ((a0 + a1) + (a2 + a3));
        x16[idx] = acc >= 0.f ? acc : NEG_SLOPE * acc;
    } else {
        int idx = (bid - 256) * 256 + threadIdx.x;   // 1032192 px total
        if (idx < 786432) {                          // g256: 2x2 box at (2r,2c)
            int o = idx;
            int c = o & 255, r = (o >> 8) & 255, bc = o >> 16;
            const float2* gp2 = (const float2*)(g + (size_t)bc * 262144);
            float2 a = gp2[(2 * r) * 256 + c];
            float2 b = gp2[(2 * r + 1) * 256 + c];
            g256p[o] = 0.25f * ((a.x + a.y) + (b.x + b.y));
        } else if (idx < 983040) {                   // g128: box at (4r+1,4c+1)
            int o = idx - 786432;
            int c = o & 127, r = (o >> 7) & 127, bc = o >> 14;
            const float* gp = g + (size_t)bc * 262144;
            int a0 = (4 * r + 1) * 512 + 4 * c + 1;
            int a1 = a0 + 512;
            g128p[o] = 0.25f * ((gp[a0] + gp[a0 + 1]) + (gp[a1] + gp[a1 + 1]));
        } else {                                     // g64: box at (8r+3,8c+3)
            int o = idx - 983040;
            int c = o & 63, r = (o >> 6) & 63, bc = o >> 12;
            const float* gp = g + (size_t)bc * 262144;
            int a0 = (8 * r + 3) * 512 + 8 * c + 3;
            int a1 = a0 + 512;
            g64p[o] = 0.25f * ((gp[a0] + gp[a0 + 1]) + (gp[a1] + gp[a1 + 1]));
        }
    }
}

// ---------------------------------------------------------------------------
// In-LDS PAC stage — verified math, all dims compile-time (no int div).
// ---------------------------------------------------------------------------
template <int Ci, int Co, int NX, int NG, int NO, int RES>
__device__ inline void pac_lds(const float* __restrict__ sx, int BXr, int BXc,
                               const float* __restrict__ sg, int BGr, int BGc,
                               const float* __restrict__ sw, float* __restrict__ so,
                               int BOr, int BOc) {
    constexpr int NG2 = NG * NG, NX2 = NX * NX, NO2 = NO * NO;
    for (int i = threadIdx.x; i < NO2; i += 256) {
        int r = i / NO, c = i % NO;
        int gh = BOr + r, gw = BOc + c;
        float acc[Co];
#pragma unroll
        for (int co = 0; co < Co; ++co) acc[co] = 0.f;
        if (gh >= 0 && gh < RES && gw >= 0 && gw < RES) {
            int lc0 = (gh - BGr) * NG + (gw - BGc);
            float gc0 = sg[lc0], gc1 = sg[NG2 + lc0], gc2 = sg[2 * NG2 + lc0];
#pragma unroll
            for (int tt = 0; tt < 9; ++tt) {
                int hh = gh + tt / 3 - 1, ww = gw + tt % 3 - 1;
                if (hh < 0 || hh >= RES || ww < 0 || ww >= RES) continue;
                int lt = (hh - BGr) * NG + (ww - BGc);
                float d0 = sg[lt] - gc0;
                float d1 = sg[NG2 + lt] - gc1;
                float d2 = sg[2 * NG2 + lt] - gc2;
                float k = __expf(-0.5f * (d0 * d0 + d1 * d1 + d2 * d2));
                int lx = ((hh >> 1) - BXr) * NX + ((ww >> 1) - BXc);
#pragma unroll
                for (int ci = 0; ci < Ci; ++ci) {
                    float xv = sx[ci * NX2 + lx] * k;
#pragma unroll
                    for (int co = 0; co < Co; ++co)
                        acc[co] = fmaf(sw[(co * Ci + ci) * 9 + tt], xv, acc[co]);
                }
            }
        }
#pragma unroll
        for (int co = 0; co < Co; ++co) {
            float v = acc[co];
            so[co * NO2 + i] = v >= 0.f ? v : NEG_SLOPE * v;
        }
    }
}

// ---------------------------------------------------------------------------
// Kernel 2: fused pac@64 + pac@128 per 16x16 x1-tile [R11-verified].
// x1 output channel-interleaved [4][128][128][4], single float4 store/px.
// ---------------------------------------------------------------------------
__global__ void __launch_bounds__(256)
pac_mid_kernel(const float* __restrict__ x16g, const float* __restrict__ g64p,
               const float* __restrict__ g128p,
               const float* __restrict__ w0, const float* __restrict__ w1,
               float* __restrict__ x1p) {
    __shared__ float smem[3100];
    float* sw0   = smem;            // 576
    float* sw1   = smem + 576;      // 144
    float* sx16  = smem + 720;      // 576  [16][6][6]
    float* sg64  = smem + 1296;     // 432  [3][12][12]
    float* sg128 = smem + 1728;     // 972  [3][18][18]
    float* sx0   = smem + 2700;     // 400  [4][10][10]

    int bid = blockIdx.x;           // 256
    int b = bid >> 6;
    int t = (bid >> 3) & 7;         // tileY
    int u = bid & 7;                // tileX

    const int BXr = 4 * t - 1,  BXc = 4 * u - 1;    // x16 (32-res), 6
    const int BG0r = 8 * t - 2, BG0c = 8 * u - 2;   // g64, 12
    const int B0r = 8 * t - 1,  B0c = 8 * u - 1;    // x0 (64-res), 10
    const int BG1r = 16 * t - 1, BG1c = 16 * u - 1; // g128, 18

    for (int i = threadIdx.x; i < 576; i += 256) sw0[i] = w0[i];
    for (int i = threadIdx.x; i < 144; i += 256) sw1[i] = w1[i];
    for (int i = threadIdx.x; i < 576; i += 256) {           // x16 [16][6][6]
        int ci = i / 36, rem = i % 36, r = rem / 6, c = rem % 6;
        int gr = BXr + r, gc = BXc + c;
        float v = 0.f;
        if (gr >= 0 && gr < 32 && gc >= 0 && gc < 32)
            v = x16g[((b * 16 + ci) << 10) + (gr << 5) + gc];
        sx16[i] = v;
    }
    for (int i = threadIdx.x; i < 432; i += 256) {           // g64 [3][12][12]
        int ch = i / 144, rem = i % 144, r = rem / 12, c = rem % 12;
        int gr = BG0r + r, gc = BG0c + c;
        float v = 0.f;
        if (gr >= 0 && gr < 64 && gc >= 0 && gc < 64)
            v = g64p[(b * 3 + ch) * 4096 + (gr << 6) + gc];
        sg64[i] = v;
    }
    for (int i = threadIdx.x; i < 972; i += 256) {           // g128 [3][18][18]
        int ch = i / 324, rem = i % 324, r = rem / 18, c = rem % 18;
        int gr = BG1r + r, gc = BG1c + c;
        float v = 0.f;
        if (gr >= 0 && gr < 128 && gc >= 0 && gc < 128)
            v = g128p[(b * 3 + ch) * 16384 + (gr << 7) + gc];
        sg128[i] = v;
    }
    __syncthreads();

    // Phase 1: x0 halo tile @64
    pac_lds<16, 4, 6, 12, 10, 64>(sx16, BXr, BXc, sg64, BG0r, BG0c, sw0, sx0, B0r, B0c);
    __syncthreads();

    // Phase 2: x1 16x16 @128 -> global packed float4 (leaky). 1 px/thread.
    {
        int i = threadIdx.x;
        int r = i >> 4, c = i & 15;
        int gh = 16 * t + r, gw = 16 * u + c;
        int lc0 = (gh - BG1r) * 18 + (gw - BG1c);
        float gc0 = sg128[lc0], gc1 = sg128[324 + lc0], gc2 = sg128[648 + lc0];
        float acc[4] = {0.f, 0.f, 0.f, 0.f};
#pragma unroll
        for (int tt = 0; tt < 9; ++tt) {
            int hh = gh + tt / 3 - 1, ww = gw + tt % 3 - 1;
            if (hh < 0 || hh >= 128 || ww < 0 || ww >= 128) continue;
            int lt = (hh - BG1r) * 18 + (ww - BG1c);
            float d0 = sg128[lt] - gc0;
            float d1 = sg128[324 + lt] - gc1;
            float d2 = sg128[648 + lt] - gc2;
            float k = __expf(-0.5f * (d0 * d0 + d1 * d1 + d2 * d2));
            int lx = ((hh >> 1) - B0r) * 10 + ((ww >> 1) - B0c);
#pragma unroll
            for (int ci = 0; ci < 4; ++ci) {
                float xv = sx0[ci * 100 + lx] * k;
#pragma unroll
                for (int co = 0; co < 4; ++co)
                    acc[co] = fmaf(sw1[(co * 4 + ci) * 9 + tt], xv, acc[co]);
            }
        }
        float4 o4;
        o4.x = acc[0] >= 0.f ? acc[0] : NEG_SLOPE * acc[0];
        o4.y = acc[1] >= 0.f ? acc[1] : NEG_SLOPE * acc[1];
        o4.z = acc[2] >= 0.f ? acc[2] : NEG_SLOPE * acc[2];
        o4.w = acc[3] >= 0.f ? acc[3] : NEG_SLOPE * acc[3];
        ((float4*)x1p)[(b << 14) + (gh << 7) + gw] = o4;
    }
}

// ---------------------------------------------------------------------------
// Kernel 3: pac 4->4 @256, one px/thread [R11-verified — reverted from the
// R12 quad experiment, which regressed ~2 µs due to shallow block queue].
// x1 input packed float4; x2 output packed float4.
// ---------------------------------------------------------------------------
__global__ void __launch_bounds__(256)
pac256_kernel(const float* __restrict__ x1p, const float* __restrict__ g,
              const float* __restrict__ wk, float* __restrict__ x2p) {
    __shared__ float sw[144];
    for (int i = threadIdx.x; i < 144; i += 256) sw[i] = wk[i];
    __syncthreads();

    constexpr int R = 256, HW = R * R;
    int idx = blockIdx.x * 256 + threadIdx.x;
    int w = idx & (R - 1);
    int h = (idx / R) & (R - 1);
    int b = idx / HW;

    const float* gb = g + (size_t)b * 3 * HW;
    int ctr = h * R + w;
    float gc0 = gb[ctr];
    float gc1 = gb[HW + ctr];
    float gc2 = gb[2 * HW + ctr];

    float acc[4] = {0.f, 0.f, 0.f, 0.f};
    const float4* xb4 = (const float4*)x1p + (size_t)b * 16384;

#pragma unroll
    for (int t = 0; t < 9; ++t) {
        int dh = t / 3 - 1, dw = t % 3 - 1;
        int hh = h + dh, ww = w + dw;
        if (hh < 0 || hh >= R || ww < 0 || ww >= R) continue;
        int tap = hh * R + ww;
        float d0 = gb[tap] - gc0;
        float d1 = gb[HW + tap] - gc1;
        float d2 = gb[2 * HW + tap] - gc2;
        float k = __expf(-0.5f * (d0 * d0 + d1 * d1 + d2 * d2));
        float4 xv4 = xb4[(hh >> 1) * 128 + (ww >> 1)];
        float xs0 = xv4.x * k, xs1 = xv4.y * k, xs2 = xv4.z * k, xs3 = xv4.w * k;
#pragma unroll
        for (int co = 0; co < 4; ++co) {
            acc[co] = fmaf(sw[(co * 4 + 0) * 9 + t], xs0, acc[co]);
            acc[co] = fmaf(sw[(co * 4 + 1) * 9 + t], xs1, acc[co]);
            acc[co] = fmaf(sw[(co * 4 + 2) * 9 + t], xs2, acc[co]);
            acc[co] = fmaf(sw[(co * 4 + 3) * 9 + t], xs3, acc[co]);
        }
    }

    float4 o4;
    o4.x = acc[0] >= 0.f ? acc[0] : NEG_SLOPE * acc[0];
    o4.y = acc[1] >= 0.f ? acc[1] : NEG_SLOPE * acc[1];
    o4.z = acc[2] >= 0.f ? acc[2] : NEG_SLOPE * acc[2];
    o4.w = acc[3] >= 0.f ? acc[3] : NEG_SLOPE * acc[3];
    ((float4*)x2p)[(b << 16) + ctr] = o4;
}

// ---------------------------------------------------------------------------
// Kernel 4: pac 4->1 @512 + sigmoid, one thread per 2x2 output quad
// [R11-verified]. x2 input packed float4.
// ---------------------------------------------------------------------------
__global__ void __launch_bounds__(256)
pac512_quad_kernel(const float* __restrict__ x2p, const float* __restrict__ guide,
                   const float* __restrict__ w3, float* __restrict__ out) {
    __shared__ float sw[36];
    if (threadIdx.x < 36) sw[threadIdx.x] = w3[threadIdx.x];
    __syncthreads();

    int idx = blockIdx.x * 256 + threadIdx.x;   // 262144 quads
    int qw = idx & 255;
    int qh = (idx >> 8) & 255;
    int b = idx >> 16;
    int h0 = qh << 1, w0 = qw << 1;

    const float* gb = guide + (size_t)b * 3 * 262144;
    const float4* xb4 = (const float4*)x2p + (size_t)b * 65536;

    float gw[3][4][4];
#pragma unroll
    for (int rr = 0; rr < 4; ++rr) {
        int gr = h0 - 1 + rr;
        bool rok = (gr >= 0 && gr < 512);
#pragma unroll
        for (int cc = 0; cc < 4; ++cc) {
            int gc = w0 - 1 + cc;
            bool ok = rok && (gc >= 0 && gc < 512);
            int a = (gr << 9) + gc;
#pragma unroll
            for (int ch = 0; ch < 3; ++ch)
                gw[ch][rr][cc] = ok ? gb[ch * 262144 + a] : 0.f;
        }
    }
    float xw[4][3][3];
#pragma unroll
    for (int rr = 0; rr < 3; ++rr) {
        int xr = qh - 1 + rr;
        bool rok = (xr >= 0 && xr < 256);
#pragma unroll
        for (int cc = 0; cc < 3; ++cc) {
            int xc = qw - 1 + cc;
            bool ok = rok && (xc >= 0 && xc < 256);
            float4 v = ok ? xb4[(xr << 8) + xc] : make_float4(0.f, 0.f, 0.f, 0.f);
            xw[0][rr][cc] = v.x;
            xw[1][rr][cc] = v.y;
            xw[2][rr][cc] = v.z;
            xw[3][rr][cc] = v.w;
        }
    }

    float* ob = out + (size_t)b * 262144;
#pragma unroll
    for (int dr = 0; dr < 2; ++dr) {
#pragma unroll
        for (int dc = 0; dc < 2; ++dc) {
            float gc0 = gw[0][dr + 1][dc + 1];
            float gc1 = gw[1][dr + 1][dc + 1];
            float gc2 = gw[2][dr + 1][dc + 1];
            float acc = 0.f;
#pragma unroll
            for (int tt = 0; tt < 9; ++tt) {
                const int th = tt / 3, tc = tt % 3;
                int hh = h0 + dr + th - 1, ww = w0 + dc + tc - 1;
                if (hh < 0 || hh >= 512 || ww < 0 || ww >= 512) continue;
                float d0 = gw[0][dr + th][dc + tc] - gc0;
                float d1 = gw[1][dr + th][dc + tc] - gc1;
                float d2 = gw[2][dr + th][dc + tc] - gc2;
                float k = __expf(-0.5f * (d0 * d0 + d1 * d1 + d2 * d2));
                const int xr = ((dr + th - 1) >> 1) + 1;
                const int xc = ((dc + tc - 1) >> 1) + 1;
#pragma unroll
                for (int ci = 0; ci < 4; ++ci)
                    acc = fmaf(sw[ci * 9 + tt], xw[ci][xr][xc] * k, acc);
            }
            ob[((h0 + dr) << 9) + (w0 + dc)] = 1.0f / (1.0f + __expf(-acc));
        }
    }
}

extern "C" void kernel_launch(void* const* d_in, const int* in_sizes, int n_in,
                              void* d_out, int out_size, void* d_ws, size_t ws_size,
                              hipStream_t stream) {
    const float* x     = (const float*)d_in[0];   // (4,384,32,32)
    const float* guide = (const float*)d_in[1];   // (4,3,512,512)
    const float* lin_w = (const float*)d_in[2];   // (16,384,1,1)
    const float* lin_b = (const float*)d_in[3];   // (16,)
    const float* w0    = (const float*)d_in[4];   // (4,16,3,3)
    const float* w1    = (const float*)d_in[5];   // (4,4,3,3)
    const float* w2    = (const float*)d_in[6];   // (4,4,3,3)
    const float* w3    = (const float*)d_in[7];   // (1,4,3,3)
    float* out = (float*)d_out;                   // (4,1,512,512)

    float* ws    = (float*)d_ws;
    float* x16   = ws;                 // 65536
    float* g64p  = x16 + 65536;        // 49152    (4,3,64,64)
    float* g128p = g64p + 49152;       // 196608   (4,3,128,128)
    float* g256p = g128p + 196608;     // 786432   (4,3,256,256)
    float* x1p   = g256p + 786432;     // 262144   (4,128,128,4) packed, 16B-aligned
    float* x2p   = x1p + 262144;       // 1048576  (4,256,256,4) packed, 16B-aligned

    prep_kernel<<<4288, 256, 0, stream>>>(x, lin_w, lin_b, x16, guide, g64p, g128p, g256p);
    pac_mid_kernel<<<256, 256, 0, stream>>>(x16, g64p, g128p, w0, w1, x1p);
    pac256_kernel<<<1024, 256, 0, stream>>>(x1p, g256p, w2, x2p);
    pac512_quad_kernel<<<1024, 256, 0, stream>>>(x2p, guide, w3, out);
}